// Round 1
// baseline (117.247 us; speedup 1.0000x reference)
//
#include <hip/hip_runtime.h>

// PointWarping2: Nadaraya-Watson regression of flow1 (at warped sources
// y = xyz1+flow1) onto queries xyz2.  B=2, C=3, N1=N2=8192, fp32.
//
// exp(-d2/s^2) computed as exp2(qc + yc + q'.y) with
//   c1 = log2(e)/s^2, qc = -c1*|q|^2 (per query), yc = -c1*|y|^2 (per source,
//   staged in LDS), q' = 2*c1*q  -> 4 VALU + 1 v_exp per pair + 4 FMA accum.

#define N1S  8192
#define N2S  8192
#define BATCH 2
#define BLK  256
#define Q    4                 // queries per thread
#define SEG  32                // segments over N1 (grid.y)
#define TILE (N1S / SEG)       // 256 sources per segment == BLK
#define QPB  (BLK * Q)         // 1024 queries per block
#define NQ   (BATCH * N2S)     // 16384 total queries
#define LOG2E 1.4426950408889634f

__device__ __forceinline__ float read_scale(const void* p) {
    // resol_factor is a 1-element array; Python int -> int32, float -> fp32.
    // Small-magnitude int bit pattern => integer; else reinterpret as float.
    int iv = *(const int*)p;
    if (iv > -(1 << 23) && iv < (1 << 23)) return (float)iv;
    return *(const float*)p;
}

__device__ __forceinline__ float fast_exp2(float x) {
#if __has_builtin(__builtin_amdgcn_exp2f)
    return __builtin_amdgcn_exp2f(x);   // raw v_exp_f32
#else
    return exp2f(x);
#endif
}

__global__ __launch_bounds__(BLK) void pw2_partial(
    const float* __restrict__ xyz1, const float* __restrict__ xyz2,
    const float* __restrict__ flow1, const void* __restrict__ resol,
    float* __restrict__ ws)
{
    __shared__ float4 sy[TILE];  // (y.x, y.y, y.z, -c1*|y|^2)
    __shared__ float4 sf[TILE];  // (f.x, f.y, f.z, 0)

    const int qbase = blockIdx.x * QPB;       // 1024 queries, single batch
    const int b     = qbase / N2S;
    const int nbase = qbase - b * N2S;
    const int seg   = blockIdx.y;
    const int t     = threadIdx.x;

    const float scale = read_scale(resol);    // INITIAL_RADIUS == 1.0
    const float c1    = LOG2E / (scale * scale);
    const float twoC  = 2.0f * c1;

    // ---- stage this segment's warped sources into LDS (TILE == BLK) ----
    {
        const int m = seg * TILE + t;
        const float* x1b = xyz1 + b * 3 * N1S;
        const float* f1b = flow1 + b * 3 * N1S;
        float fx = f1b[0 * N1S + m], fy = f1b[1 * N1S + m], fz = f1b[2 * N1S + m];
        float yx = x1b[0 * N1S + m] + fx;
        float yy = x1b[1 * N1S + m] + fy;
        float yz = x1b[2 * N1S + m] + fz;
        float yc = -c1 * (yx * yx + yy * yy + yz * yz);
        sy[t] = make_float4(yx, yy, yz, yc);
        sf[t] = make_float4(fx, fy, fz, 0.f);
    }
    __syncthreads();

    // ---- per-thread query state ----
    float qx[Q], qy[Q], qz[Q], qc[Q];
    float ax[Q], ay[Q], az[Q], aw[Q];
    const float* x2b = xyz2 + b * 3 * N2S;
#pragma unroll
    for (int j = 0; j < Q; ++j) {
        int n = nbase + t + j * BLK;
        float x = x2b[0 * N2S + n], y = x2b[1 * N2S + n], z = x2b[2 * N2S + n];
        qc[j] = -c1 * (x * x + y * y + z * z);
        qx[j] = twoC * x; qy[j] = twoC * y; qz[j] = twoC * z;
        ax[j] = ay[j] = az[j] = aw[j] = 0.f;
    }

    // ---- main loop: LDS-broadcast sources, 8 independent exp chains ----
#pragma unroll 2
    for (int s = 0; s < TILE; ++s) {
        float4 ya = sy[s];
        float4 fa = sf[s];
#pragma unroll
        for (int j = 0; j < Q; ++j) {
            float arg = qc[j] + ya.w;
            arg = fmaf(qx[j], ya.x, arg);
            arg = fmaf(qy[j], ya.y, arg);
            arg = fmaf(qz[j], ya.z, arg);
            float w = fast_exp2(arg);
            ax[j] = fmaf(w, fa.x, ax[j]);
            ay[j] = fmaf(w, fa.y, ay[j]);
            az[j] = fmaf(w, fa.z, az[j]);
            aw[j] += w;
        }
    }

    // ---- cross-segment reduction: 32 collisions per address ----
#pragma unroll
    for (int j = 0; j < Q; ++j) {
        int q = qbase + t + j * BLK;
        atomicAdd(&ws[4 * q + 0], ax[j]);
        atomicAdd(&ws[4 * q + 1], ay[j]);
        atomicAdd(&ws[4 * q + 2], az[j]);
        atomicAdd(&ws[4 * q + 3], aw[j]);
    }
}

__global__ __launch_bounds__(256) void pw2_final(
    const float* __restrict__ xyz2, const float* __restrict__ ws,
    float* __restrict__ out)
{
    int q = blockIdx.x * blockDim.x + threadIdx.x;
    if (q >= NQ) return;
    int b = q / N2S, n = q - b * N2S;
    const float* x2b = xyz2 + b * 3 * N2S;
    float4 p = ((const float4*)ws)[q];
    float inv = 1.0f / p.w;
    out[b * 3 * N2S + 0 * N2S + n] = x2b[0 * N2S + n] - p.x * inv;
    out[b * 3 * N2S + 1 * N2S + n] = x2b[1 * N2S + n] - p.y * inv;
    out[b * 3 * N2S + 2 * N2S + n] = x2b[2 * N2S + n] - p.z * inv;
}

extern "C" void kernel_launch(void* const* d_in, const int* in_sizes, int n_in,
                              void* d_out, int out_size, void* d_ws, size_t ws_size,
                              hipStream_t stream) {
    const float* xyz1  = (const float*)d_in[0];
    const float* xyz2  = (const float*)d_in[1];
    const float* flow1 = (const float*)d_in[2];
    const void*  resol = d_in[3];
    float* ws  = (float*)d_ws;
    float* out = (float*)d_out;

    hipMemsetAsync(ws, 0, (size_t)NQ * 4 * sizeof(float), stream);

    dim3 grid(NQ / QPB, SEG);   // 16 x 32 = 512 blocks
    pw2_partial<<<grid, BLK, 0, stream>>>(xyz1, xyz2, flow1, resol, ws);

    pw2_final<<<(NQ + 255) / 256, 256, 0, stream>>>(xyz2, ws, out);
}

// Round 2
// 101.764 us; speedup vs baseline: 1.1522x; 1.1522x over previous
//
#include <hip/hip_runtime.h>

// PointWarping2 fused single-kernel: Nadaraya-Watson regression of flow1
// (at warped sources y = xyz1+flow1) onto queries xyz2. B=2,C=3,N1=N2=8192 fp32.
//
// Layout: 1024 blocks x 256 thr. Block owns QB=16 queries, ALL 8192 sources.
//   wave 0: queries 0-7,  sources [0,128) of each tile
//   wave 1: queries 0-7,  sources [128,256)
//   wave 2: queries 8-15, sources [0,128)
//   wave 3: queries 8-15, sources [128,256)
// Query constants are wave-uniform; lanes are source-parallel; each staged
// float4 source is reused for 8 queries in registers (LDS stays cheap).
// exp(-d2/s^2) = exp2(qc + yc + q'.y): 4 VALU + v_exp + 4 accum FMA per pair.

#define N1S  8192
#define N2S  8192
#define BATCH 2
#define BLK  256
#define TILE 256
#define NTILE (N1S / TILE)     // 32
#define QB   16                // queries per block
#define QT   8                 // queries per thread
#define NQ   (BATCH * N2S)
#define LOG2E 1.4426950408889634f

__device__ __forceinline__ float read_scale(const void* p) {
    // resol_factor: 1-elem array; Python int -> int32, float -> fp32.
    int iv = *(const int*)p;
    if (iv > -(1 << 23) && iv < (1 << 23)) return (float)iv;
    return *(const float*)p;
}

__device__ __forceinline__ float fast_exp2(float x) {
#if __has_builtin(__builtin_amdgcn_exp2f)
    return __builtin_amdgcn_exp2f(x);   // raw v_exp_f32
#else
    return exp2f(x);
#endif
}

__global__ __launch_bounds__(BLK, 4) void pw2_fused(
    const float* __restrict__ xyz1, const float* __restrict__ xyz2,
    const float* __restrict__ flow1, const void* __restrict__ resol,
    float* __restrict__ out)
{
    __shared__ float4 sy[2][TILE];   // (y.x,y.y,y.z, -c1*|y|^2), double-buffered
    __shared__ float4 sf[2][TILE];   // (f.x,f.y,f.z, 0)
    __shared__ float  red[4][4 * QT];

    const int t = threadIdx.x;
    const int w = t >> 6;            // wave 0..3
    const int l = t & 63;
    const int g = w >> 1;            // query group
    const int h = w & 1;             // source half

    const int qbase = blockIdx.x * QB;
    const int b     = qbase / N2S;
    const int nbase = qbase - b * N2S;

    const float scale = read_scale(resol);   // INITIAL_RADIUS == 1.0
    const float c1    = LOG2E / (scale * scale);
    const float twoC  = 2.0f * c1;

    const float* x1b = xyz1  + b * 3 * N1S;
    const float* f1b = flow1 + b * 3 * N1S;
    const float* x2b = xyz2  + b * 3 * N2S;

    // ---- per-thread (wave-uniform) query constants ----
    float qx[QT], qy[QT], qz[QT], qc[QT];
    float ax[QT], ay[QT], az[QT], aw[QT];
#pragma unroll
    for (int j = 0; j < QT; ++j) {
        int n = nbase + g * QT + j;
        float x = x2b[0*N2S+n], y = x2b[1*N2S+n], z = x2b[2*N2S+n];
        qc[j] = -c1 * (x*x + y*y + z*z);
        qx[j] = twoC*x; qy[j] = twoC*y; qz[j] = twoC*z;
        ax[j] = ay[j] = az[j] = aw[j] = 0.f;
    }

    // ---- stage tile 0 ----
    {
        float fx = f1b[0*N1S+t], fy = f1b[1*N1S+t], fz = f1b[2*N1S+t];
        float yx = x1b[0*N1S+t]+fx, yy = x1b[1*N1S+t]+fy, yz = x1b[2*N1S+t]+fz;
        float yc = -c1*(yx*yx + yy*yy + yz*yz);
        sy[0][t] = make_float4(yx, yy, yz, yc);
        sf[0][t] = make_float4(fx, fy, fz, 0.f);
    }
    __syncthreads();

    // ---- main loop: double-buffered tiles ----
    for (int tt = 0; tt < NTILE; ++tt) {
        const int  cur  = tt & 1;
        const bool more = (tt + 1) < NTILE;
        float fx, fy, fz, yx, yy, yz;
        if (more) {                       // issue next tile's global loads now
            int m = (tt + 1) * TILE + t;
            fx = f1b[0*N1S+m]; fy = f1b[1*N1S+m]; fz = f1b[2*N1S+m];
            yx = x1b[0*N1S+m]+fx; yy = x1b[1*N1S+m]+fy; yz = x1b[2*N1S+m]+fz;
        }
#pragma unroll
        for (int k = 0; k < 2; ++k) {     // 2 sources per lane per tile
            float4 ya = sy[cur][h*128 + k*64 + l];
            float4 fa = sf[cur][h*128 + k*64 + l];
#pragma unroll
            for (int j = 0; j < QT; ++j) {
                float arg = qc[j] + ya.w;
                arg = fmaf(qx[j], ya.x, arg);
                arg = fmaf(qy[j], ya.y, arg);
                arg = fmaf(qz[j], ya.z, arg);
                float wgt = fast_exp2(arg);
                ax[j] = fmaf(wgt, fa.x, ax[j]);
                ay[j] = fmaf(wgt, fa.y, ay[j]);
                az[j] = fmaf(wgt, fa.z, az[j]);
                aw[j] += wgt;
            }
        }
        if (more) {                       // write next tile into the other buffer
            float yc = -c1*(yx*yx + yy*yy + yz*yz);
            sy[cur^1][t] = make_float4(yx, yy, yz, yc);
            sf[cur^1][t] = make_float4(fx, fy, fz, 0.f);
        }
        __syncthreads();
    }

    // ---- reduce across the 64 source-lanes of each wave ----
#pragma unroll
    for (int j = 0; j < QT; ++j) {
#pragma unroll
        for (int off = 1; off < 64; off <<= 1) {
            ax[j] += __shfl_xor(ax[j], off, 64);
            ay[j] += __shfl_xor(ay[j], off, 64);
            az[j] += __shfl_xor(az[j], off, 64);
            aw[j] += __shfl_xor(aw[j], off, 64);
        }
    }
    if (l == 0) {
#pragma unroll
        for (int j = 0; j < QT; ++j) {
            red[w][4*j+0] = ax[j]; red[w][4*j+1] = ay[j];
            red[w][4*j+2] = az[j]; red[w][4*j+3] = aw[j];
        }
    }
    __syncthreads();

    // ---- combine the two source-halves, normalize, write ----
    if (t < QB) {
        int gg = t >> 3, jj = t & 7;
        float nx = red[2*gg][4*jj+0] + red[2*gg+1][4*jj+0];
        float ny = red[2*gg][4*jj+1] + red[2*gg+1][4*jj+1];
        float nz = red[2*gg][4*jj+2] + red[2*gg+1][4*jj+2];
        float dn = red[2*gg][4*jj+3] + red[2*gg+1][4*jj+3];
        float inv = 1.0f / dn;
        int n = nbase + t;
        out[b*3*N2S + 0*N2S + n] = x2b[0*N2S+n] - nx*inv;
        out[b*3*N2S + 1*N2S + n] = x2b[1*N2S+n] - ny*inv;
        out[b*3*N2S + 2*N2S + n] = x2b[2*N2S+n] - nz*inv;
    }
}

extern "C" void kernel_launch(void* const* d_in, const int* in_sizes, int n_in,
                              void* d_out, int out_size, void* d_ws, size_t ws_size,
                              hipStream_t stream) {
    const float* xyz1  = (const float*)d_in[0];
    const float* xyz2  = (const float*)d_in[1];
    const float* flow1 = (const float*)d_in[2];
    const void*  resol = d_in[3];
    float* out = (float*)d_out;

    pw2_fused<<<NQ / QB, BLK, 0, stream>>>(xyz1, xyz2, flow1, resol, out);
}